// Round 19
// baseline (222.840 us; speedup 1.0000x reference)
//
#include <hip/hip_runtime.h>
#include <hip/hip_bf16.h>

#define N_ 8
#define C_ 64
#define H_ 128
#define W_ 256
#define HW_ (H_*W_)        // 32768
#define CHW_ (C_*H_*W_)    // 2097152

typedef unsigned int u32;
typedef unsigned short u16;
typedef float f32x4 __attribute__((ext_vector_type(4)));
typedef short bf16x8 __attribute__((ext_vector_type(8)));

__device__ __forceinline__ float blo(u32 u) { return __uint_as_float(u << 16); }
__device__ __forceinline__ float bhi(u32 u) { return __uint_as_float(u & 0xffff0000u); }
__device__ __forceinline__ u16 f2bf(float f) {
    u32 u = __float_as_uint(f);
    u32 lsb = (u >> 16) & 1u;
    u += 0x7fffu + lsb;
    return (u16)(u >> 16);
}
__device__ __forceinline__ u32 pack2(float a, float b) {
    return (u32)f2bf(a) | ((u32)f2bf(b) << 16);
}
__device__ __forceinline__ int rmap(int px) {
    return (px & 0xF8) | ((px + (px >> 3)) & 7);
}

// ---------------------------------------------------------------------------
// K_FUSED (1024 threads / 16 waves): r18 structure with per-wave work halved
// (r11 transformation repeated).  Wave (mw=wv&3, nh=wv>>2) does GEMM m-tile
// mw over n-quarter nh (4 nt); attention wave owns 16 queries.  Same 69KB
// LDS now hosts 16 resident waves (4/SIMD).
// ---------------------------------------------------------------------------
__global__ __launch_bounds__(1024, 1) void k_fused(
    const float* __restrict__ xl, const float* __restrict__ xr,
    const float* __restrict__ nlw, const float* __restrict__ nlb,
    const float* __restrict__ nrw, const float* __restrict__ nrb,
    const float* __restrict__ Wql, const float* __restrict__ bql,
    const float* __restrict__ Wqr, const float* __restrict__ bqr,
    const float* __restrict__ Wvr, const float* __restrict__ bvr,
    const float* __restrict__ beta, float* __restrict__ out)
{
    __shared__ u32 B1[8192];           // 32 KB: X_l -> X_r -> Ks
    __shared__ u32 B2[8192];           // 32 KB: Q_l -> Vts
    __shared__ float muA[256], rsA[256];
    __shared__ float SlA[64], BlA[64], SrA[64], BrA[64], BvA[64];
    const int tid  = threadIdx.x;
    const int lane = tid & 63, wv = tid >> 6;    // wv 0..15
    const int l15  = lane & 15, kg = lane >> 4;
    const int mw   = wv & 3;           // GEMM m-tile
    const int nh   = wv >> 2;          // GEMM n-quarter (0..3)
    const int blk  = blockIdx.x;       // n*128 + h
    const int n = blk >> 7, h = blk & 127;
    const size_t gbase = (size_t)n*CHW_ + (size_t)h*W_;

    if (tid < 64) {
        const int o = tid;
        float sl = 0.f, bl = bql[o], sr = 0.f, br = bqr[o];
        for (int c = 0; c < 64; ++c) {
            float wl = Wql[o*64+c], wr = Wqr[o*64+c];
            sl += wl * nlw[c];
            bl += wl * nlb[c];
            sr += wr * nrw[c];
            br += wr * nrb[c];
        }
        SlA[o] = sl; BlA[o] = bl; SrA[o] = sr; BrA[o] = br; BvA[o] = bvr[o];
    }

    const int oA = mw*16 + l15;
    bf16x8 aL[2], aR[2], aV[2];
    #pragma unroll
    for (int hf = 0; hf < 2; ++hf) {
        bf16x8 tl, tr, tv;
        #pragma unroll
        for (int j = 0; j < 8; ++j) {
            const int c = hf*32 + kg*8 + j;
            tl[j] = (short)f2bf(Wql[oA*64+c] * nlw[c]);
            tr[j] = (short)f2bf(Wqr[oA*64+c] * nrw[c]);
            tv[j] = (short)f2bf(Wvr[oA*64+c]);
        }
        aL[hf] = tl; aR[hf] = tr; aV[hf] = tv;
    }

    // staging decomposition: 1024 threads, thread = (chunk4, j) ->
    // 4 channels (c0 = chunk4*4) x 4 px (j*4..+3); uint2 LDS writes.
    const int chunk4 = tid >> 6;            // 0..15
    const int schunk = chunk4 >> 1;         // uint4 slot 0..7
    const int ssub   = chunk4 & 1;          // which uint2 within slot
    const int sj     = tid & 63;            // px group

    // ================= LEFT: stage xl =================
    {
        const int c0 = chunk4*4;
        float4 v[4];
        #pragma unroll
        for (int e = 0; e < 4; ++e)
            v[e] = *(const float4*)(xl + gbase + (size_t)(c0+e)*HW_ + sj*4);
        #pragma unroll
        for (int t = 0; t < 4; ++t) {
            const int px = sj*4 + t;
            const int r = rmap(px);
            u32 q0,q1;
            const float* f0 = (const float*)&v[0]; const float* f1 = (const float*)&v[1];
            const float* f2 = (const float*)&v[2]; const float* f3 = (const float*)&v[3];
            asm("v_cvt_pk_bf16_f32 %0, %1, %2" : "=v"(q0) : "v"(f0[t]), "v"(f1[t]));
            asm("v_cvt_pk_bf16_f32 %0, %1, %2" : "=v"(q1) : "v"(f2[t]), "v"(f3[t]));
            uint2 pv; pv.x=q0; pv.y=q1;
            *(uint2*)&B1[r*32 + ((schunk ^ (r&7))<<2) + ssub*2] = pv;
        }
    }
    // ---- T14: prefetch xr now ----
    float4 vr2[4];
    {
        const int c0 = chunk4*4;
        #pragma unroll
        for (int e = 0; e < 4; ++e)
            vr2[e] = *(const float4*)(xr + gbase + (size_t)(c0+e)*HW_ + sj*4);
    }
    __syncthreads();                                    // b1
    if (tid < 256) {   // LN stats (left)
        const int px = tid;
        const int r = rmap(px);
        float sum = 0.f, ssq = 0.f;
        #pragma unroll
        for (int c8 = 0; c8 < 8; ++c8) {
            uint4 val = *(const uint4*)&B1[r*32 + ((c8 ^ (r&7))<<2)];
            const u32* wp = (const u32*)&val;
            #pragma unroll
            for (int q = 0; q < 4; ++q) {
                float a = blo(wp[q]), b = bhi(wp[q]);
                sum += a + b; ssq += a*a + b*b;
            }
        }
        float mu = sum * (1.f/64.f);
        float var = ssq * (1.f/64.f) - mu*mu;
        muA[px] = mu;
        rsA[px] = rsqrtf(var + 1e-6f);
    }
    __syncthreads();                                    // b2
    {   // GEMM left -> Q_l into B2; 4 nt per wave
        float Sv[4], Bv[4];
        #pragma unroll
        for (int r4 = 0; r4 < 4; ++r4) {
            Sv[r4] = SlA[mw*16 + kg*4 + r4];
            Bv[r4] = BlA[mw*16 + kg*4 + r4];
        }
        #pragma unroll
        for (int nt2 = 0; nt2 < 4; ++nt2) {
            const int nt = nh*4 + nt2;
            const int px = nt*16 + l15;
            const int r = rmap(px);
            f32x4 d = {0.f,0.f,0.f,0.f};
            #pragma unroll
            for (int hf = 0; hf < 2; ++hf) {
                bf16x8 b = *(const bf16x8*)&B1[r*32 + (((hf*4+kg) ^ (r&7))<<2)];
                d = __builtin_amdgcn_mfma_f32_16x16x32_bf16(aL[hf], b, d, 0, 0, 0);
            }
            const float mu = muA[px], rs = rsA[px];
            uint2 pv;
            pv.x = pack2(rs*(d[0] - mu*Sv[0]) + Bv[0], rs*(d[1] - mu*Sv[1]) + Bv[1]);
            pv.y = pack2(rs*(d[2] - mu*Sv[2]) + Bv[2], rs*(d[3] - mu*Sv[3]) + Bv[3]);
            const int ci = (mw*2 + (kg>>1)) ^ (px & 7);
            *(uint2*)&B2[px*32 + (ci<<2) + (kg&1)*2] = pv;
        }
    }
    __syncthreads();                                    // b3

    // ---- qf fragments (16 queries) from B2; write prefetched xr into B1 ----
    bf16x8 qf[2];
    #pragma unroll
    for (int ci = 0; ci < 2; ++ci) {
        const int q = wv*16 + l15;
        qf[ci] = *(const bf16x8*)&B2[q*32 + (((ci*4+kg) ^ (q&7))<<2)];
    }
    {
        #pragma unroll
        for (int t = 0; t < 4; ++t) {
            const int px = sj*4 + t;
            const int r = rmap(px);
            u32 q0,q1;
            const float* f0 = (const float*)&vr2[0]; const float* f1 = (const float*)&vr2[1];
            const float* f2 = (const float*)&vr2[2]; const float* f3 = (const float*)&vr2[3];
            asm("v_cvt_pk_bf16_f32 %0, %1, %2" : "=v"(q0) : "v"(f0[t]), "v"(f1[t]));
            asm("v_cvt_pk_bf16_f32 %0, %1, %2" : "=v"(q1) : "v"(f2[t]), "v"(f3[t]));
            uint2 pv; pv.x=q0; pv.y=q1;
            *(uint2*)&B1[r*32 + ((schunk ^ (r&7))<<2) + ssub*2] = pv;
        }
    }
    __syncthreads();                                    // b4
    if (tid < 256) {   // LN stats (right)
        const int px = tid;
        const int r = rmap(px);
        float sum = 0.f, ssq = 0.f;
        #pragma unroll
        for (int c8 = 0; c8 < 8; ++c8) {
            uint4 val = *(const uint4*)&B1[r*32 + ((c8 ^ (r&7))<<2)];
            const u32* wp = (const u32*)&val;
            #pragma unroll
            for (int q = 0; q < 4; ++q) {
                float a = blo(wp[q]), b = bhi(wp[q]);
                sum += a + b; ssq += a*a + b*b;
            }
        }
        float mu = sum * (1.f/64.f);
        float var = ssq * (1.f/64.f) - mu*mu;
        muA[px] = mu;
        rsA[px] = rsqrtf(var + 1e-6f);
    }
    __syncthreads();                                    // b5

    // ---- GEMM right: outputs HELD in regs (4 nt per wave) ----
    u32 hq[4][2], hv[4][2];
    {
        float Sv[4], Bv[4];
        #pragma unroll
        for (int r4 = 0; r4 < 4; ++r4) {
            Sv[r4] = SrA[mw*16 + kg*4 + r4];
            Bv[r4] = BrA[mw*16 + kg*4 + r4];
        }
        const int chv = mw*16 + l15;
        const float vbias = BvA[chv];
        #pragma unroll
        for (int nt2 = 0; nt2 < 4; ++nt2) {
            const int nt = nh*4 + nt2;
            const int px = nt*16 + l15;
            const int r = rmap(px);
            bf16x8 bX[2];
            #pragma unroll
            for (int hf = 0; hf < 2; ++hf)
                bX[hf] = *(const bf16x8*)&B1[r*32 + (((hf*4+kg) ^ (r&7))<<2)];
            f32x4 dq = {0.f,0.f,0.f,0.f};
            f32x4 dv = {0.f,0.f,0.f,0.f};
            #pragma unroll
            for (int hf = 0; hf < 2; ++hf) {
                dq = __builtin_amdgcn_mfma_f32_16x16x32_bf16(aR[hf], bX[hf], dq, 0, 0, 0);
                dv = __builtin_amdgcn_mfma_f32_16x16x32_bf16(bX[hf], aV[hf], dv, 0, 0, 0);
            }
            const float mu = muA[px], rs = rsA[px];
            hq[nt2][0] = pack2(rs*(dq[0] - mu*Sv[0]) + Bv[0], rs*(dq[1] - mu*Sv[1]) + Bv[1]);
            hq[nt2][1] = pack2(rs*(dq[2] - mu*Sv[2]) + Bv[2], rs*(dq[3] - mu*Sv[3]) + Bv[3]);
            hv[nt2][0] = pack2(dv[0] + vbias, dv[1] + vbias);
            hv[nt2][1] = pack2(dv[2] + vbias, dv[3] + vbias);
        }
    }
    __syncthreads();                                    // b6
    {   // write Ks over B1 (X_r dead), Vts over B2 (Q_l in qf regs)
        const int chv = mw*16 + l15;
        u16* Vts16 = (u16*)B2;
        #pragma unroll
        for (int nt2 = 0; nt2 < 4; ++nt2) {
            const int nt = nh*4 + nt2;
            const int px = nt*16 + l15;
            const int ciq = (mw*2 + (kg>>1)) ^ (px & 7);
            uint2 pq; pq.x = hq[nt2][0]; pq.y = hq[nt2][1];
            *(uint2*)&B1[px*32 + (ciq<<2) + (kg&1)*2] = pq;
            uint2 pw; pw.x = hv[nt2][0]; pw.y = hv[nt2][1];
            const int swz = (nt*2 + (kg>>1)) ^ (chv & 7);
            *(uint2*)&Vts16[chv*256 + (swz<<3) + (kg&1)*4] = pw;
        }
    }
    __syncthreads();                                    // b7

    // ================= ATTENTION (shuffle-P; wave owns 16 queries) =========
    f32x4 oacc[4];
    #pragma unroll
    for (int b = 0; b < 4; ++b)
        oacc[b] = (f32x4){0.f,0.f,0.f,0.f};
    float lsum = 0.f;
    const uint4* KsR = (const uint4*)B1;
    const u16* Vts = (const u16*)B2;
    const int srcA = ((2*kg) & 3)*16 + l15;   // shuffle source lane

    for (int kb = 0; kb < 8; ++kb) {
        f32x4 st[2];                    // [mt]
        st[0] = (f32x4){0.f,0.f,0.f,0.f};
        st[1] = (f32x4){0.f,0.f,0.f,0.f};
        #pragma unroll
        for (int ci = 0; ci < 2; ++ci) {
            bf16x8 a0 = *(const bf16x8*)&KsR[(kb*32 +      l15)*8 + ((ci*4 + kg) ^ (l15 & 7))];
            bf16x8 a1 = *(const bf16x8*)&KsR[(kb*32 + 16 + l15)*8 + ((ci*4 + kg) ^ (l15 & 7))];
            st[0] = __builtin_amdgcn_mfma_f32_16x16x32_bf16(a0, qf[ci], st[0], 0, 0, 0);
            st[1] = __builtin_amdgcn_mfma_f32_16x16x32_bf16(a1, qf[ci], st[1], 0, 0, 0);
        }
        // exp + pack + shuffle-redistribute into PV A-fragment
        bf16x8 paR;
        {
            float p00 = __expf(st[0][0]*0.125f);
            float p01 = __expf(st[0][1]*0.125f);
            float p02 = __expf(st[0][2]*0.125f);
            float p03 = __expf(st[0][3]*0.125f);
            float p10 = __expf(st[1][0]*0.125f);
            float p11 = __expf(st[1][1]*0.125f);
            float p12 = __expf(st[1][2]*0.125f);
            float p13 = __expf(st[1][3]*0.125f);
            lsum += ((p00+p01)+(p02+p03)) + ((p10+p11)+(p12+p13));
            u32 pk00, pk01, pk10, pk11;
            asm("v_cvt_pk_bf16_f32 %0, %1, %2" : "=v"(pk00) : "v"(p00), "v"(p01));
            asm("v_cvt_pk_bf16_f32 %0, %1, %2" : "=v"(pk01) : "v"(p02), "v"(p03));
            asm("v_cvt_pk_bf16_f32 %0, %1, %2" : "=v"(pk10) : "v"(p10), "v"(p11));
            asm("v_cvt_pk_bf16_f32 %0, %1, %2" : "=v"(pk11) : "v"(p12), "v"(p13));
            int a00 = __shfl((int)pk00, srcA, 64);
            int a01 = __shfl((int)pk01, srcA, 64);
            int a10 = __shfl((int)pk10, srcA, 64);
            int a11 = __shfl((int)pk11, srcA, 64);
            int b00 = __shfl((int)pk00, srcA + 16, 64);
            int b01 = __shfl((int)pk01, srcA + 16, 64);
            int b10 = __shfl((int)pk10, srcA + 16, 64);
            int b11 = __shfl((int)pk11, srcA + 16, 64);
            const bool lo = (kg < 2);
            union { u32 u[4]; bf16x8 v; } pu;
            pu.u[0] = (u32)(lo ? a00 : a10);
            pu.u[1] = (u32)(lo ? a01 : a11);
            pu.u[2] = (u32)(lo ? b00 : b10);
            pu.u[3] = (u32)(lo ? b01 : b11);
            paR = pu.v;
        }
        bf16x8 vb[4];
        #pragma unroll
        for (int nc = 0; nc < 4; ++nc)
            vb[nc] = *(const bf16x8*)&Vts[(nc*16 + l15)*256 + ((kb*4 + kg) ^ (l15 & 7))*8];
        #pragma unroll
        for (int nc = 0; nc < 4; ++nc)
            oacc[nc] = __builtin_amdgcn_mfma_f32_16x16x32_bf16(paR, vb[nc], oacc[nc], 0, 0, 0);
    }

    {
        float s = lsum;
        s += __shfl_xor(s, 16, 64);
        s += __shfl_xor(s, 32, 64);
        lsum = s;
    }
    float linv[4];
    #pragma unroll
    for (int r = 0; r < 4; ++r)
        linv[r] = 1.0f / __shfl(lsum, kg*4 + r, 64);

    // ---- epilogue: out = xl + beta*F (pure store on out; xl L3-warm) ----
    const size_t qbase = gbase + wv*16;
    #pragma unroll
    for (int nc = 0; nc < 4; ++nc) {
        const int ch = nc*16 + l15;
        const float bch = beta[ch];
        const size_t gidx = qbase + (size_t)ch*HW_ + kg*4;
        f32x4 x4 = *(const f32x4*)&xl[gidx];
        f32x4 vals;
        #pragma unroll
        for (int r = 0; r < 4; ++r)
            vals[r] = x4[r] + bch*(oacc[nc][r]*linv[r]);
        *(f32x4*)&out[gidx] = vals;
    }
}

// ---------------------------------------------------------------------------
// K3: T_t[n][h][w][c] = highpass(x_r), bf16 (unchanged, validated).
// ---------------------------------------------------------------------------
__global__ __launch_bounds__(256) void k_hipass(
    const float* __restrict__ xr, u16* __restrict__ Tt)
{
    __shared__ u16 Ts[64*256];             // 32 KB
    const int bid = blockIdx.x;
    const int blk = (bid & 7)*128 + (bid >> 3);   // XCD chunk: 128 rows/XCD
    const int n = blk >> 7, h = blk & 127;
    const int tid = threadIdx.x;
    const int lane = tid & 63, wv = tid >> 6;
    const float* rowp = xr + (size_t)n*CHW_ + (size_t)h*W_ + lane*4;

    #pragma unroll
    for (int ci = 0; ci < 16; ++ci) {
        const int c = wv*16 + ci;
        const float* pc = rowp + (size_t)c*HW_;
        float ctr0=0.f, ctr1=0.f, ctr2=0.f, ctr3=0.f;
        float s0=0.f, s1=0.f, s2=0.f, s3=0.f;
        #pragma unroll
        for (int dy = -1; dy <= 1; ++dy) {
            const int hh = h + dy;
            float4 v = {0.f,0.f,0.f,0.f};
            if (hh >= 0 && hh < 128) v = *(const float4*)(pc + dy*W_);
            float lft = __shfl_up(v.w, 1);
            float rgt = __shfl_down(v.x, 1);
            if (lane == 0)  lft = 0.f;
            if (lane == 63) rgt = 0.f;
            s0 += lft + v.x + v.y;
            s1 += v.x + v.y + v.z;
            s2 += v.y + v.z + v.w;
            s3 += v.z + v.w + rgt;
            if (dy == 0) { ctr0=v.x; ctr1=v.y; ctr2=v.z; ctr3=v.w; }
        }
        uint2 pv;
        pv.x = pack2(ctr0 - s0*(1.f/9.f), ctr1 - s1*(1.f/9.f));
        pv.y = pack2(ctr2 - s2*(1.f/9.f), ctr3 - s3*(1.f/9.f));
        const int swz = (c >> 3) << 3;                 // chunk<<3
        *(uint2*)&Ts[c*256 + ((lane*4) ^ swz)] = pv;
    }
    __syncthreads();
    uint4* gout = (uint4*)(Tt + (size_t)blk*256*64);
    #pragma unroll
    for (int iter = 0; iter < 8; ++iter) {
        const int lin = iter*256 + tid;
        const int px = lin >> 3, chunk = lin & 7;
        const int pxs = px ^ (chunk << 3);
        u32 w4[4];
        #pragma unroll
        for (int tp = 0; tp < 4; ++tp) {
            const int c0 = chunk*8 + tp*2;
            u16 a = Ts[(c0    )*256 + pxs];
            u16 b = Ts[(c0 + 1)*256 + pxs];
            w4[tp] = (u32)a | ((u32)b << 16);
        }
        uint4 v; v.x=w4[0]; v.y=w4[1]; v.z=w4[2]; v.w=w4[3];
        gout[lin] = v;
    }
}

// ---------------------------------------------------------------------------
// K4: conv3x3 as MFMA GEMM (r15 form: out += gamma*(hf+b), L3-hot RMW).
// ---------------------------------------------------------------------------
__device__ __forceinline__ void conv_tile(
    const uint4* __restrict__ buf, const bf16x8* A,
    const float* gv, const float* bv,
    int n, int h, int w0, int mt, int l15, int kg,
    float* __restrict__ out)
{
    f32x4 acc[4] = {{0,0,0,0},{0,0,0,0},{0,0,0,0},{0,0,0,0}};
    #pragma unroll
    for (int s = 0; s < 18; ++s) {
        const int q  = s >> 1;
        const int dy = q / 3, dx = q % 3;
        const int c0 = (s & 1)*4 + kg;
        #pragma unroll
        for (int nt = 0; nt < 4; ++nt) {
            const int wt = nt*16 + l15 + dx;
            bf16x8 b = *(const bf16x8*)&buf[(dy*66 + wt)*8 + (c0 ^ (wt & 7))];
            acc[nt] = __builtin_amdgcn_mfma_f32_16x16x32_bf16(A[s], b, acc[nt], 0, 0, 0);
        }
    }
    #pragma unroll
    for (int nt = 0; nt < 4; ++nt) {
        const int px = w0 + nt*16 + l15;
        #pragma unroll
        for (int r = 0; r < 4; ++r) {
            const int oo = mt*16 + kg*4 + r;
            size_t idx = (size_t)(n*64 + oo)*HW_ + (size_t)h*W_ + px;
            out[idx] += gv[r]*(acc[nt][r] + bv[r]);
        }
    }
}

__global__ __launch_bounds__(256) void k_conv(
    const u16* __restrict__ Tt, const float* __restrict__ Whf,
    const float* __restrict__ bhf, const float* __restrict__ gam,
    float* __restrict__ out)
{
    __shared__ uint4 Xs[2][1584];          // 2 x 25344 B double buffer
    const int tid  = threadIdx.x;
    const int lane = tid & 63;
    const int mt   = tid >> 6;
    const int l15  = lane & 15;
    const int kg   = lane >> 4;
    const int bid  = blockIdx.x;
    const int blk2 = (bid & 7)*256 + (bid >> 3);   // XCD chunk swizzle (2048 wgs)
    const int row  = blk2 >> 1, half = blk2 & 1;
    const int n = row >> 7, h = row & 127;
    const int w00 = half*128;
    const int w01 = w00 + 64;

    const int oa = mt*16 + l15;
    bf16x8 A[18];
    #pragma unroll
    for (int s = 0; s < 18; ++s) {
        const int q  = s >> 1;
        const int ib = (s & 1)*32 + kg*8;
        bf16x8 a;
        #pragma unroll
        for (int j = 0; j < 8; ++j) {
            float wv = Whf[(size_t)(oa*64 + ib + j)*9 + q];
            a[j] = (short)f2bf(wv);
        }
        A[s] = a;
    }
    float gv[4], bv[4];
    #pragma unroll
    for (int r = 0; r < 4; ++r) {
        int oo = mt*16 + kg*4 + r;
        gv[r] = gam[oo];
        bv[r] = bhf[oo];
    }

    for (int it = tid; it < 1584; it += 256) {
        int dy    = it / 528;
        int rem   = it - dy*528;
        int wt    = rem >> 3;
        int chunk = rem & 7;
        int hh = h + dy - 1;
        int wg = w00 + wt - 1;
        uint4 v = {0,0,0,0};
        if (hh >= 0 && hh < 128 && wg >= 0 && wg < 256)
            v = *(const uint4*)(Tt + (((size_t)(n*128 + hh)*256 + wg)*64 + chunk*8));
        Xs[0][(dy*66 + wt)*8 + (chunk ^ (wt & 7))] = v;
    }
    __syncthreads();

    uint4 rr[7];
    #pragma unroll
    for (int k = 0; k < 7; ++k) {
        const int it = k*256 + tid;
        if (it < 1584) {
            int dy    = it / 528;
            int rem   = it - dy*528;
            int wt    = rem >> 3;
            int chunk = rem & 7;
            int hh = h + dy - 1;
            int wg = w01 + wt - 1;
            uint4 v = {0,0,0,0};
            if (hh >= 0 && hh < 128 && wg >= 0 && wg < 256)
                v = *(const uint4*)(Tt + (((size_t)(n*128 + hh)*256 + wg)*64 + chunk*8));
            rr[k] = v;
        }
    }

    conv_tile(&Xs[0][0], A, gv, bv, n, h, w00, mt, l15, kg, out);

    #pragma unroll
    for (int k = 0; k < 7; ++k) {
        const int it = k*256 + tid;
        if (it < 1584) {
            int dy    = it / 528;
            int rem   = it - dy*528;
            int wt    = rem >> 3;
            int chunk = rem & 7;
            Xs[1][(dy*66 + wt)*8 + (chunk ^ (wt & 7))] = rr[k];
        }
    }
    __syncthreads();
    conv_tile(&Xs[1][0], A, gv, bv, n, h, w01, mt, l15, kg, out);
}

extern "C" void kernel_launch(void* const* d_in, const int* in_sizes, int n_in,
                              void* d_out, int out_size, void* d_ws, size_t ws_size,
                              hipStream_t stream)
{
    const float* xl   = (const float*)d_in[0];
    const float* xr   = (const float*)d_in[1];
    const float* nlw  = (const float*)d_in[2];
    const float* nlb  = (const float*)d_in[3];
    const float* nrw  = (const float*)d_in[4];
    const float* nrb  = (const float*)d_in[5];
    const float* Wql  = (const float*)d_in[6];
    const float* bql  = (const float*)d_in[7];
    const float* Wqr  = (const float*)d_in[8];
    const float* bqr  = (const float*)d_in[9];
    const float* Wvr  = (const float*)d_in[10];
    const float* bvr  = (const float*)d_in[11];
    const float* beta = (const float*)d_in[12];
    const float* gam  = (const float*)d_in[13];
    const float* Whf  = (const float*)d_in[14];
    const float* bhf  = (const float*)d_in[15];
    float* out = (float*)d_out;

    u16* Tt = (u16*)d_ws;    // 33 MB; Q/K/V never touch HBM

    k_hipass<<<1024, 256, 0, stream>>>(xr, Tt);
    k_fused<<<1024, 1024, 0, stream>>>(xl, xr, nlw, nlb, nrw, nrb,
                                       Wql, bql, Wqr, bqr, Wvr, bvr,
                                       beta, out);
    k_conv<<<2048, 256, 0, stream>>>(Tt, Whf, bhf, gam, out);
}

// Round 20
// 174.740 us; speedup vs baseline: 1.2753x; 1.2753x over previous
//
#include <hip/hip_runtime.h>
#include <hip/hip_bf16.h>

#define N_ 8
#define C_ 64
#define H_ 128
#define W_ 256
#define HW_ (H_*W_)        // 32768
#define CHW_ (C_*H_*W_)    // 2097152

typedef unsigned int u32;
typedef unsigned short u16;
typedef float f32x4 __attribute__((ext_vector_type(4)));
typedef short bf16x8 __attribute__((ext_vector_type(8)));

__device__ __forceinline__ float blo(u32 u) { return __uint_as_float(u << 16); }
__device__ __forceinline__ float bhi(u32 u) { return __uint_as_float(u & 0xffff0000u); }
__device__ __forceinline__ u16 f2bf(float f) {
    u32 u = __float_as_uint(f);
    u32 lsb = (u >> 16) & 1u;
    u += 0x7fffu + lsb;
    return (u16)(u >> 16);
}
__device__ __forceinline__ u32 pack2(float a, float b) {
    return (u32)f2bf(a) | ((u32)f2bf(b) << 16);
}
__device__ __forceinline__ int rmap(int px) {
    return (px & 0xF8) | ((px + (px >> 3)) & 7);
}

// ---------------------------------------------------------------------------
// K_FUSED (512 threads / 8 waves): r15 structure + r16's validated
// xr register-prefetch.  Epilogue: out = xl + beta*F (pure store on out);
// k_conv then RMW-adds gamma*hf.   [r18 validated optimum: 175.2 us total]
// ---------------------------------------------------------------------------
__global__ __launch_bounds__(512, 2) void k_fused(
    const float* __restrict__ xl, const float* __restrict__ xr,
    const float* __restrict__ nlw, const float* __restrict__ nlb,
    const float* __restrict__ nrw, const float* __restrict__ nrb,
    const float* __restrict__ Wql, const float* __restrict__ bql,
    const float* __restrict__ Wqr, const float* __restrict__ bqr,
    const float* __restrict__ Wvr, const float* __restrict__ bvr,
    const float* __restrict__ beta, float* __restrict__ out)
{
    __shared__ u32 B1[8192];           // 32 KB: X_l -> X_r -> Ks
    __shared__ u32 B2[8192];           // 32 KB: Q_l -> Vts
    __shared__ float muA[256], rsA[256];
    __shared__ float SlA[64], BlA[64], SrA[64], BrA[64], BvA[64];
    const int tid  = threadIdx.x;
    const int lane = tid & 63, wv = tid >> 6;
    const int l15  = lane & 15, kg = lane >> 4;
    const int mw   = wv & 3;           // GEMM m-tile
    const int nh   = wv >> 2;          // GEMM n-half (0/1)
    const int blk  = blockIdx.x;       // n*128 + h
    const int n = blk >> 7, h = blk & 127;
    const size_t gbase = (size_t)n*CHW_ + (size_t)h*W_;

    if (tid < 64) {
        const int o = tid;
        float sl = 0.f, bl = bql[o], sr = 0.f, br = bqr[o];
        for (int c = 0; c < 64; ++c) {
            float wl = Wql[o*64+c], wr = Wqr[o*64+c];
            sl += wl * nlw[c];
            bl += wl * nlb[c];
            sr += wr * nrw[c];
            br += wr * nrb[c];
        }
        SlA[o] = sl; BlA[o] = bl; SrA[o] = sr; BrA[o] = br; BvA[o] = bvr[o];
    }

    const int oA = mw*16 + l15;
    bf16x8 aL[2], aR[2], aV[2];
    #pragma unroll
    for (int hf = 0; hf < 2; ++hf) {
        bf16x8 tl, tr, tv;
        #pragma unroll
        for (int j = 0; j < 8; ++j) {
            const int c = hf*32 + kg*8 + j;
            tl[j] = (short)f2bf(Wql[oA*64+c] * nlw[c]);
            tr[j] = (short)f2bf(Wqr[oA*64+c] * nrw[c]);
            tv[j] = (short)f2bf(Wvr[oA*64+c]);
        }
        aL[hf] = tl; aR[hf] = tr; aV[hf] = tv;
    }

    const int schunk = tid >> 6;       // staging: channel chunk
    const int sj     = tid & 63;       // staging: px group

    // ================= LEFT: stage xl =================
    {
        const int c0 = schunk*8;
        float4 v[8];
        #pragma unroll
        for (int e = 0; e < 8; ++e)
            v[e] = *(const float4*)(xl + gbase + (size_t)(c0+e)*HW_ + sj*4);
        #pragma unroll
        for (int t = 0; t < 4; ++t) {
            const int px = sj*4 + t;
            const int r = rmap(px);
            u32 q0,q1,q2,q3;
            const float* f0 = (const float*)&v[0]; const float* f1 = (const float*)&v[1];
            const float* f2 = (const float*)&v[2]; const float* f3 = (const float*)&v[3];
            const float* f4 = (const float*)&v[4]; const float* f5 = (const float*)&v[5];
            const float* f6 = (const float*)&v[6]; const float* f7 = (const float*)&v[7];
            asm("v_cvt_pk_bf16_f32 %0, %1, %2" : "=v"(q0) : "v"(f0[t]), "v"(f1[t]));
            asm("v_cvt_pk_bf16_f32 %0, %1, %2" : "=v"(q1) : "v"(f2[t]), "v"(f3[t]));
            asm("v_cvt_pk_bf16_f32 %0, %1, %2" : "=v"(q2) : "v"(f4[t]), "v"(f5[t]));
            asm("v_cvt_pk_bf16_f32 %0, %1, %2" : "=v"(q3) : "v"(f6[t]), "v"(f7[t]));
            uint4 pv; pv.x=q0; pv.y=q1; pv.z=q2; pv.w=q3;
            *(uint4*)&B1[r*32 + ((schunk ^ (r&7))<<2)] = pv;
        }
    }
    // ---- T14 (validated r16): prefetch xr now; hides under L phases ----
    float4 vr2[8];
    {
        const int c0 = schunk*8;
        #pragma unroll
        for (int e = 0; e < 8; ++e)
            vr2[e] = *(const float4*)(xr + gbase + (size_t)(c0+e)*HW_ + sj*4);
    }
    __syncthreads();                                    // b1
    if (tid < 256) {   // LN stats (left)
        const int px = tid;
        const int r = rmap(px);
        float sum = 0.f, ssq = 0.f;
        #pragma unroll
        for (int c8 = 0; c8 < 8; ++c8) {
            uint4 val = *(const uint4*)&B1[r*32 + ((c8 ^ (r&7))<<2)];
            const u32* wp = (const u32*)&val;
            #pragma unroll
            for (int q = 0; q < 4; ++q) {
                float a = blo(wp[q]), b = bhi(wp[q]);
                sum += a + b; ssq += a*a + b*b;
            }
        }
        float mu = sum * (1.f/64.f);
        float var = ssq * (1.f/64.f) - mu*mu;
        muA[px] = mu;
        rsA[px] = rsqrtf(var + 1e-6f);
    }
    __syncthreads();                                    // b2
    {   // GEMM left -> Q_l into B2 [row][ch] swizzled; 8 nt per wave
        float Sv[4], Bv[4];
        #pragma unroll
        for (int r4 = 0; r4 < 4; ++r4) {
            Sv[r4] = SlA[mw*16 + kg*4 + r4];
            Bv[r4] = BlA[mw*16 + kg*4 + r4];
        }
        #pragma unroll
        for (int nt2 = 0; nt2 < 8; ++nt2) {
            const int nt = nh*8 + nt2;
            const int px = nt*16 + l15;
            const int r = rmap(px);
            f32x4 d = {0.f,0.f,0.f,0.f};
            #pragma unroll
            for (int hf = 0; hf < 2; ++hf) {
                bf16x8 b = *(const bf16x8*)&B1[r*32 + (((hf*4+kg) ^ (r&7))<<2)];
                d = __builtin_amdgcn_mfma_f32_16x16x32_bf16(aL[hf], b, d, 0, 0, 0);
            }
            const float mu = muA[px], rs = rsA[px];
            uint2 pv;
            pv.x = pack2(rs*(d[0] - mu*Sv[0]) + Bv[0], rs*(d[1] - mu*Sv[1]) + Bv[1]);
            pv.y = pack2(rs*(d[2] - mu*Sv[2]) + Bv[2], rs*(d[3] - mu*Sv[3]) + Bv[3]);
            const int ci = (mw*2 + (kg>>1)) ^ (px & 7);
            *(uint2*)&B2[px*32 + (ci<<2) + (kg&1)*2] = pv;
        }
    }
    __syncthreads();                                    // b3

    // ---- qf fragments from B2; write PREFETCHED xr into B1 ----
    bf16x8 qf[2][2];
    #pragma unroll
    for (int ntq = 0; ntq < 2; ++ntq)
        #pragma unroll
        for (int ci = 0; ci < 2; ++ci) {
            const int q = wv*32 + ntq*16 + l15;
            qf[ntq][ci] = *(const bf16x8*)&B2[q*32 + (((ci*4+kg) ^ (q&7))<<2)];
        }
    {
        #pragma unroll
        for (int t = 0; t < 4; ++t) {
            const int px = sj*4 + t;
            const int r = rmap(px);
            u32 q0,q1,q2,q3;
            const float* f0 = (const float*)&vr2[0]; const float* f1 = (const float*)&vr2[1];
            const float* f2 = (const float*)&vr2[2]; const float* f3 = (const float*)&vr2[3];
            const float* f4 = (const float*)&vr2[4]; const float* f5 = (const float*)&vr2[5];
            const float* f6 = (const float*)&vr2[6]; const float* f7 = (const float*)&vr2[7];
            asm("v_cvt_pk_bf16_f32 %0, %1, %2" : "=v"(q0) : "v"(f0[t]), "v"(f1[t]));
            asm("v_cvt_pk_bf16_f32 %0, %1, %2" : "=v"(q1) : "v"(f2[t]), "v"(f3[t]));
            asm("v_cvt_pk_bf16_f32 %0, %1, %2" : "=v"(q2) : "v"(f4[t]), "v"(f5[t]));
            asm("v_cvt_pk_bf16_f32 %0, %1, %2" : "=v"(q3) : "v"(f6[t]), "v"(f7[t]));
            uint4 pv; pv.x=q0; pv.y=q1; pv.z=q2; pv.w=q3;
            *(uint4*)&B1[r*32 + ((schunk ^ (r&7))<<2)] = pv;
        }
    }
    __syncthreads();                                    // b4
    if (tid < 256) {   // LN stats (right)
        const int px = tid;
        const int r = rmap(px);
        float sum = 0.f, ssq = 0.f;
        #pragma unroll
        for (int c8 = 0; c8 < 8; ++c8) {
            uint4 val = *(const uint4*)&B1[r*32 + ((c8 ^ (r&7))<<2)];
            const u32* wp = (const u32*)&val;
            #pragma unroll
            for (int q = 0; q < 4; ++q) {
                float a = blo(wp[q]), b = bhi(wp[q]);
                sum += a + b; ssq += a*a + b*b;
            }
        }
        float mu = sum * (1.f/64.f);
        float var = ssq * (1.f/64.f) - mu*mu;
        muA[px] = mu;
        rsA[px] = rsqrtf(var + 1e-6f);
    }
    __syncthreads();                                    // b5

    // ---- GEMM right: outputs HELD in regs (balanced, 8 nt per wave) ----
    u32 hq[8][2], hv[8][2];
    {
        float Sv[4], Bv[4];
        #pragma unroll
        for (int r4 = 0; r4 < 4; ++r4) {
            Sv[r4] = SrA[mw*16 + kg*4 + r4];
            Bv[r4] = BrA[mw*16 + kg*4 + r4];
        }
        const int chv = mw*16 + l15;
        const float vbias = BvA[chv];
        #pragma unroll
        for (int nt2 = 0; nt2 < 8; ++nt2) {
            const int nt = nh*8 + nt2;
            const int px = nt*16 + l15;
            const int r = rmap(px);
            bf16x8 bX[2];
            #pragma unroll
            for (int hf = 0; hf < 2; ++hf)
                bX[hf] = *(const bf16x8*)&B1[r*32 + (((hf*4+kg) ^ (r&7))<<2)];
            f32x4 dq = {0.f,0.f,0.f,0.f};
            f32x4 dv = {0.f,0.f,0.f,0.f};
            #pragma unroll
            for (int hf = 0; hf < 2; ++hf) {
                dq = __builtin_amdgcn_mfma_f32_16x16x32_bf16(aR[hf], bX[hf], dq, 0, 0, 0);
                dv = __builtin_amdgcn_mfma_f32_16x16x32_bf16(bX[hf], aV[hf], dv, 0, 0, 0);
            }
            const float mu = muA[px], rs = rsA[px];
            hq[nt2][0] = pack2(rs*(dq[0] - mu*Sv[0]) + Bv[0], rs*(dq[1] - mu*Sv[1]) + Bv[1]);
            hq[nt2][1] = pack2(rs*(dq[2] - mu*Sv[2]) + Bv[2], rs*(dq[3] - mu*Sv[3]) + Bv[3]);
            hv[nt2][0] = pack2(dv[0] + vbias, dv[1] + vbias);
            hv[nt2][1] = pack2(dv[2] + vbias, dv[3] + vbias);
        }
    }
    __syncthreads();                                    // b6
    {   // write Ks over B1 (X_r dead), Vts over B2 (Q_l in qf regs)
        const int chv = mw*16 + l15;
        u16* Vts16 = (u16*)B2;
        #pragma unroll
        for (int nt2 = 0; nt2 < 8; ++nt2) {
            const int nt = nh*8 + nt2;
            const int px = nt*16 + l15;
            const int ciq = (mw*2 + (kg>>1)) ^ (px & 7);
            uint2 pq; pq.x = hq[nt2][0]; pq.y = hq[nt2][1];
            *(uint2*)&B1[px*32 + (ciq<<2) + (kg&1)*2] = pq;
            uint2 pw; pw.x = hv[nt2][0]; pw.y = hv[nt2][1];
            const int swz = (nt*2 + (kg>>1)) ^ (chv & 7);
            *(uint2*)&Vts16[chv*256 + (swz<<3) + (kg&1)*4] = pw;
        }
    }
    __syncthreads();                                    // b7

    // ================= ATTENTION (shuffle-P, no LDS P) =================
    f32x4 oacc[2][4];
    #pragma unroll
    for (int a = 0; a < 2; ++a)
        #pragma unroll
        for (int b = 0; b < 4; ++b)
            oacc[a][b] = (f32x4){0.f,0.f,0.f,0.f};
    float lsum[2] = {0.f,0.f};
    const uint4* KsR = (const uint4*)B1;
    const u16* Vts = (const u16*)B2;
    const int srcA = ((2*kg) & 3)*16 + l15;   // shuffle source lane

    for (int kb = 0; kb < 8; ++kb) {
        f32x4 st[2][2];                 // [mt][ntq]
        #pragma unroll
        for (int mt = 0; mt < 2; ++mt)
            #pragma unroll
            for (int nt = 0; nt < 2; ++nt)
                st[mt][nt] = (f32x4){0.f,0.f,0.f,0.f};
        #pragma unroll
        for (int ci = 0; ci < 2; ++ci) {
            bf16x8 a0 = *(const bf16x8*)&KsR[(kb*32 +      l15)*8 + ((ci*4 + kg) ^ (l15 & 7))];
            bf16x8 a1 = *(const bf16x8*)&KsR[(kb*32 + 16 + l15)*8 + ((ci*4 + kg) ^ (l15 & 7))];
            #pragma unroll
            for (int nt = 0; nt < 2; ++nt) {
                st[0][nt] = __builtin_amdgcn_mfma_f32_16x16x32_bf16(a0, qf[nt][ci], st[0][nt], 0, 0, 0);
                st[1][nt] = __builtin_amdgcn_mfma_f32_16x16x32_bf16(a1, qf[nt][ci], st[1][nt], 0, 0, 0);
            }
        }
        bf16x8 paR[2];
        #pragma unroll
        for (int nt = 0; nt < 2; ++nt) {
            float p00 = __expf(st[0][nt][0]*0.125f);
            float p01 = __expf(st[0][nt][1]*0.125f);
            float p02 = __expf(st[0][nt][2]*0.125f);
            float p03 = __expf(st[0][nt][3]*0.125f);
            float p10 = __expf(st[1][nt][0]*0.125f);
            float p11 = __expf(st[1][nt][1]*0.125f);
            float p12 = __expf(st[1][nt][2]*0.125f);
            float p13 = __expf(st[1][nt][3]*0.125f);
            lsum[nt] += ((p00+p01)+(p02+p03)) + ((p10+p11)+(p12+p13));
            u32 pk00, pk01, pk10, pk11;
            asm("v_cvt_pk_bf16_f32 %0, %1, %2" : "=v"(pk00) : "v"(p00), "v"(p01));
            asm("v_cvt_pk_bf16_f32 %0, %1, %2" : "=v"(pk01) : "v"(p02), "v"(p03));
            asm("v_cvt_pk_bf16_f32 %0, %1, %2" : "=v"(pk10) : "v"(p10), "v"(p11));
            asm("v_cvt_pk_bf16_f32 %0, %1, %2" : "=v"(pk11) : "v"(p12), "v"(p13));
            int a00 = __shfl((int)pk00, srcA, 64);
            int a01 = __shfl((int)pk01, srcA, 64);
            int a10 = __shfl((int)pk10, srcA, 64);
            int a11 = __shfl((int)pk11, srcA, 64);
            int b00 = __shfl((int)pk00, srcA + 16, 64);
            int b01 = __shfl((int)pk01, srcA + 16, 64);
            int b10 = __shfl((int)pk10, srcA + 16, 64);
            int b11 = __shfl((int)pk11, srcA + 16, 64);
            const bool lo = (kg < 2);
            union { u32 u[4]; bf16x8 v; } pu;
            pu.u[0] = (u32)(lo ? a00 : a10);
            pu.u[1] = (u32)(lo ? a01 : a11);
            pu.u[2] = (u32)(lo ? b00 : b10);
            pu.u[3] = (u32)(lo ? b01 : b11);
            paR[nt] = pu.v;
        }
        bf16x8 vb[4];
        #pragma unroll
        for (int nc = 0; nc < 4; ++nc)
            vb[nc] = *(const bf16x8*)&Vts[(nc*16 + l15)*256 + ((kb*4 + kg) ^ (l15 & 7))*8];
        #pragma unroll
        for (int qt = 0; qt < 2; ++qt)
            #pragma unroll
            for (int nc = 0; nc < 4; ++nc)
                oacc[qt][nc] = __builtin_amdgcn_mfma_f32_16x16x32_bf16(paR[qt], vb[nc], oacc[qt][nc], 0, 0, 0);
    }

    #pragma unroll
    for (int nt = 0; nt < 2; ++nt) {
        float s = lsum[nt];
        s += __shfl_xor(s, 16, 64);
        s += __shfl_xor(s, 32, 64);
        lsum[nt] = s;
    }
    float linv[2][4];
    #pragma unroll
    for (int qt = 0; qt < 2; ++qt)
        #pragma unroll
        for (int r = 0; r < 4; ++r)
            linv[qt][r] = 1.0f / __shfl(lsum[qt], kg*4 + r, 64);

    // ---- epilogue: out = xl + beta*F (pure store on out; xl L3-warm) ----
    const size_t qbase = gbase + wv*32;
    #pragma unroll
    for (int nc = 0; nc < 4; ++nc) {
        const int ch = nc*16 + l15;
        const float bch = beta[ch];
        #pragma unroll
        for (int qt = 0; qt < 2; ++qt) {
            const size_t gidx = qbase + (size_t)ch*HW_ + qt*16 + kg*4;
            f32x4 x4 = *(const f32x4*)&xl[gidx];
            f32x4 vals;
            #pragma unroll
            for (int r = 0; r < 4; ++r)
                vals[r] = x4[r] + bch*(oacc[qt][nc][r]*linv[qt][r]);
            *(f32x4*)&out[gidx] = vals;
        }
    }
}

// ---------------------------------------------------------------------------
// K3: T_t[n][h][w][c] = highpass(x_r), bf16 (unchanged, validated).
// ---------------------------------------------------------------------------
__global__ __launch_bounds__(256) void k_hipass(
    const float* __restrict__ xr, u16* __restrict__ Tt)
{
    __shared__ u16 Ts[64*256];             // 32 KB
    const int bid = blockIdx.x;
    const int blk = (bid & 7)*128 + (bid >> 3);   // XCD chunk: 128 rows/XCD
    const int n = blk >> 7, h = blk & 127;
    const int tid = threadIdx.x;
    const int lane = tid & 63, wv = tid >> 6;
    const float* rowp = xr + (size_t)n*CHW_ + (size_t)h*W_ + lane*4;

    #pragma unroll
    for (int ci = 0; ci < 16; ++ci) {
        const int c = wv*16 + ci;
        const float* pc = rowp + (size_t)c*HW_;
        float ctr0=0.f, ctr1=0.f, ctr2=0.f, ctr3=0.f;
        float s0=0.f, s1=0.f, s2=0.f, s3=0.f;
        #pragma unroll
        for (int dy = -1; dy <= 1; ++dy) {
            const int hh = h + dy;
            float4 v = {0.f,0.f,0.f,0.f};
            if (hh >= 0 && hh < 128) v = *(const float4*)(pc + dy*W_);
            float lft = __shfl_up(v.w, 1);
            float rgt = __shfl_down(v.x, 1);
            if (lane == 0)  lft = 0.f;
            if (lane == 63) rgt = 0.f;
            s0 += lft + v.x + v.y;
            s1 += v.x + v.y + v.z;
            s2 += v.y + v.z + v.w;
            s3 += v.z + v.w + rgt;
            if (dy == 0) { ctr0=v.x; ctr1=v.y; ctr2=v.z; ctr3=v.w; }
        }
        uint2 pv;
        pv.x = pack2(ctr0 - s0*(1.f/9.f), ctr1 - s1*(1.f/9.f));
        pv.y = pack2(ctr2 - s2*(1.f/9.f), ctr3 - s3*(1.f/9.f));
        const int swz = (c >> 3) << 3;                 // chunk<<3
        *(uint2*)&Ts[c*256 + ((lane*4) ^ swz)] = pv;
    }
    __syncthreads();
    uint4* gout = (uint4*)(Tt + (size_t)blk*256*64);
    #pragma unroll
    for (int iter = 0; iter < 8; ++iter) {
        const int lin = iter*256 + tid;
        const int px = lin >> 3, chunk = lin & 7;
        const int pxs = px ^ (chunk << 3);
        u32 w4[4];
        #pragma unroll
        for (int tp = 0; tp < 4; ++tp) {
            const int c0 = chunk*8 + tp*2;
            u16 a = Ts[(c0    )*256 + pxs];
            u16 b = Ts[(c0 + 1)*256 + pxs];
            w4[tp] = (u32)a | ((u32)b << 16);
        }
        uint4 v; v.x=w4[0]; v.y=w4[1]; v.z=w4[2]; v.w=w4[3];
        gout[lin] = v;
    }
}

// ---------------------------------------------------------------------------
// K4: conv3x3 as MFMA GEMM (r15 form: out += gamma*(hf+b), L3-hot RMW).
// ---------------------------------------------------------------------------
__device__ __forceinline__ void conv_tile(
    const uint4* __restrict__ buf, const bf16x8* A,
    const float* gv, const float* bv,
    int n, int h, int w0, int mt, int l15, int kg,
    float* __restrict__ out)
{
    f32x4 acc[4] = {{0,0,0,0},{0,0,0,0},{0,0,0,0},{0,0,0,0}};
    #pragma unroll
    for (int s = 0; s < 18; ++s) {
        const int q  = s >> 1;
        const int dy = q / 3, dx = q % 3;
        const int c0 = (s & 1)*4 + kg;
        #pragma unroll
        for (int nt = 0; nt < 4; ++nt) {
            const int wt = nt*16 + l15 + dx;
            bf16x8 b = *(const bf16x8*)&buf[(dy*66 + wt)*8 + (c0 ^ (wt & 7))];
            acc[nt] = __builtin_amdgcn_mfma_f32_16x16x32_bf16(A[s], b, acc[nt], 0, 0, 0);
        }
    }
    #pragma unroll
    for (int nt = 0; nt < 4; ++nt) {
        const int px = w0 + nt*16 + l15;
        #pragma unroll
        for (int r = 0; r < 4; ++r) {
            const int oo = mt*16 + kg*4 + r;
            size_t idx = (size_t)(n*64 + oo)*HW_ + (size_t)h*W_ + px;
            out[idx] += gv[r]*(acc[nt][r] + bv[r]);
        }
    }
}

__global__ __launch_bounds__(256) void k_conv(
    const u16* __restrict__ Tt, const float* __restrict__ Whf,
    const float* __restrict__ bhf, const float* __restrict__ gam,
    float* __restrict__ out)
{
    __shared__ uint4 Xs[2][1584];          // 2 x 25344 B double buffer
    const int tid  = threadIdx.x;
    const int lane = tid & 63;
    const int mt   = tid >> 6;
    const int l15  = lane & 15;
    const int kg   = lane >> 4;
    const int bid  = blockIdx.x;
    const int blk2 = (bid & 7)*256 + (bid >> 3);   // XCD chunk swizzle (2048 wgs)
    const int row  = blk2 >> 1, half = blk2 & 1;
    const int n = row >> 7, h = row & 127;
    const int w00 = half*128;
    const int w01 = w00 + 64;

    const int oa = mt*16 + l15;
    bf16x8 A[18];
    #pragma unroll
    for (int s = 0; s < 18; ++s) {
        const int q  = s >> 1;
        const int ib = (s & 1)*32 + kg*8;
        bf16x8 a;
        #pragma unroll
        for (int j = 0; j < 8; ++j) {
            float wv = Whf[(size_t)(oa*64 + ib + j)*9 + q];
            a[j] = (short)f2bf(wv);
        }
        A[s] = a;
    }
    float gv[4], bv[4];
    #pragma unroll
    for (int r = 0; r < 4; ++r) {
        int oo = mt*16 + kg*4 + r;
        gv[r] = gam[oo];
        bv[r] = bhf[oo];
    }

    for (int it = tid; it < 1584; it += 256) {
        int dy    = it / 528;
        int rem   = it - dy*528;
        int wt    = rem >> 3;
        int chunk = rem & 7;
        int hh = h + dy - 1;
        int wg = w00 + wt - 1;
        uint4 v = {0,0,0,0};
        if (hh >= 0 && hh < 128 && wg >= 0 && wg < 256)
            v = *(const uint4*)(Tt + (((size_t)(n*128 + hh)*256 + wg)*64 + chunk*8));
        Xs[0][(dy*66 + wt)*8 + (chunk ^ (wt & 7))] = v;
    }
    __syncthreads();

    uint4 rr[7];
    #pragma unroll
    for (int k = 0; k < 7; ++k) {
        const int it = k*256 + tid;
        if (it < 1584) {
            int dy    = it / 528;
            int rem   = it - dy*528;
            int wt    = rem >> 3;
            int chunk = rem & 7;
            int hh = h + dy - 1;
            int wg = w01 + wt - 1;
            uint4 v = {0,0,0,0};
            if (hh >= 0 && hh < 128 && wg >= 0 && wg < 256)
                v = *(const uint4*)(Tt + (((size_t)(n*128 + hh)*256 + wg)*64 + chunk*8));
            rr[k] = v;
        }
    }

    conv_tile(&Xs[0][0], A, gv, bv, n, h, w00, mt, l15, kg, out);

    #pragma unroll
    for (int k = 0; k < 7; ++k) {
        const int it = k*256 + tid;
        if (it < 1584) {
            int dy    = it / 528;
            int rem   = it - dy*528;
            int wt    = rem >> 3;
            int chunk = rem & 7;
            Xs[1][(dy*66 + wt)*8 + (chunk ^ (wt & 7))] = rr[k];
        }
    }
    __syncthreads();
    conv_tile(&Xs[1][0], A, gv, bv, n, h, w01, mt, l15, kg, out);
}

extern "C" void kernel_launch(void* const* d_in, const int* in_sizes, int n_in,
                              void* d_out, int out_size, void* d_ws, size_t ws_size,
                              hipStream_t stream)
{
    const float* xl   = (const float*)d_in[0];
    const float* xr   = (const float*)d_in[1];
    const float* nlw  = (const float*)d_in[2];
    const float* nlb  = (const float*)d_in[3];
    const float* nrw  = (const float*)d_in[4];
    const float* nrb  = (const float*)d_in[5];
    const float* Wql  = (const float*)d_in[6];
    const float* bql  = (const float*)d_in[7];
    const float* Wqr  = (const float*)d_in[8];
    const float* bqr  = (const float*)d_in[9];
    const float* Wvr  = (const float*)d_in[10];
    const float* bvr  = (const float*)d_in[11];
    const float* beta = (const float*)d_in[12];
    const float* gam  = (const float*)d_in[13];
    const float* Whf  = (const float*)d_in[14];
    const float* bhf  = (const float*)d_in[15];
    float* out = (float*)d_out;

    u16* Tt = (u16*)d_ws;    // 33 MB; Q/K/V never touch HBM

    k_hipass<<<1024, 256, 0, stream>>>(xr, Tt);
    k_fused<<<1024, 512, 0, stream>>>(xl, xr, nlw, nlb, nrw, nrb,
                                      Wql, bql, Wqr, bqr, Wvr, bvr,
                                      beta, out);
    k_conv<<<2048, 256, 0, stream>>>(Tt, Whf, bhf, gam, out);
}